// Round 6
// baseline (322.703 us; speedup 1.0000x reference)
//
#include <hip/hip_runtime.h>

// TinyAttention on MI355X, round 13.
//   K0: cvt x/qkv_w/proj_w fp32->fp16
//   K1: QKV GEMM, m97-style global_load_lds(16B) DMA
//   K2: flash attn = r12 (PV-direct 16x16x16 + T14 async-STAGE split) with
//       __launch_bounds__(256,3): r12's (256,4) pinned VGPR=64 and the 16
//       prefetch regs spilled to scratch (WRITE_SIZE +16.8MB = 64B x 262144
//       threads, exact). (256,3) releases the allocator; occupancy is
//       grid-limited at 4 blocks/CU anyway (VGPR<=128 keeps 16 waves/CU).
//   K3: proj GEMM, m97-style, fp32 out
// B=4 T=2048 C=1024 H=16 hd=64. Inputs fp32, output fp32 (established r1-r3).

typedef _Float16 f16x8 __attribute__((ext_vector_type(8)));
typedef _Float16 f16x4 __attribute__((ext_vector_type(4)));
typedef __fp16 h16x2 __attribute__((ext_vector_type(2)));  // cvt_pkrtz native type
typedef float f32x4 __attribute__((ext_vector_type(4)));

__device__ __forceinline__ uint4 cvt8h(const float* p) {
    float4 a = *(const float4*)p, b = *(const float4*)(p + 4);
    union { _Float16 h[8]; uint4 u; } t;
    t.h[0] = (_Float16)a.x; t.h[1] = (_Float16)a.y;
    t.h[2] = (_Float16)a.z; t.h[3] = (_Float16)a.w;
    t.h[4] = (_Float16)b.x; t.h[5] = (_Float16)b.y;
    t.h[6] = (_Float16)b.z; t.h[7] = (_Float16)b.w;
    return t.u;
}

// async global->LDS DMA, 16 B/lane; LDS dest = wave-uniform base + lane*16
__device__ __forceinline__ void dma16(const _Float16* g, _Float16* l) {
    __builtin_amdgcn_global_load_lds(
        (const __attribute__((address_space(1))) unsigned int*)g,
        (__attribute__((address_space(3))) unsigned int*)l, 16, 0, 0);
}

// ---------------- K0: fp32 -> fp16 convert ----------------
__global__ __launch_bounds__(256) void cvt_fp16(
    const float* __restrict__ x, const float* __restrict__ w1,
    const float* __restrict__ w2,
    _Float16* __restrict__ xh, _Float16* __restrict__ w1h,
    _Float16* __restrict__ w2h)
{
    const int g = blockIdx.x * 256 + threadIdx.x;
    const float* src; _Float16* dst; int off;
    if (g < 1048576)      { src = x;  dst = xh;  off = g; }
    else if (g < 1441792) { src = w1; dst = w1h; off = g - 1048576; }
    else                  { src = w2; dst = w2h; off = g - 1441792; }
    const size_t e = (size_t)off * 8;
    *(uint4*)(dst + e) = cvt8h(src + e);
}

// ---------------- K1: QKV GEMM (m97 structure) ----------------
// M=8192 N=3072 K=1024. q pre-scaled by 0.125*log2e; v transposed [bh][d][t].
__global__ __launch_bounds__(256) void qkv_gemm(
    const _Float16* __restrict__ X, const _Float16* __restrict__ W,
    const float* __restrict__ Bias,
    _Float16* __restrict__ qws, _Float16* __restrict__ kws,
    _Float16* __restrict__ vtws)
{
    __shared__ _Float16 sA[128 * 32];   // 8 KB, unpadded (DMA layout)
    __shared__ _Float16 sB[128 * 32];
    const int tid = threadIdx.x;
    const int wave = tid >> 6, lane = tid & 63;
    const int wm = (wave >> 1) * 64, wn = (wave & 1) * 64;
    const int lr = lane & 15, lq = lane >> 4;
    const int m0 = blockIdx.y * 128, n0 = blockIdx.x * 128;
    const int s = n0 >> 10;

    const int drow = wave * 16 + (lane >> 2);
    const int dcol = (lane & 3) * 8;
    _Float16* ldsA = sA + wave * 512;
    _Float16* ldsB = sB + wave * 512;
    const _Float16* gA = X + (size_t)(m0 + drow) * 1024 + dcol;
    const _Float16* gB = W + (size_t)(n0 + drow) * 1024 + dcol;

    f32x4 acc[4][4] = {};

    for (int k0 = 0; k0 < 1024; k0 += 32) {
        dma16(gA + k0, ldsA);
        dma16(gA + (size_t)64 * 1024 + k0, ldsA + 2048);
        dma16(gB + k0, ldsB);
        dma16(gB + (size_t)64 * 1024 + k0, ldsB + 2048);
        __syncthreads();  // drains DMA for all waves
        f16x8 af[4], bf[4];
        #pragma unroll
        for (int i = 0; i < 4; ++i) {
            af[i] = *(const f16x8*)&sA[(wm + i * 16 + lr) * 32 + lq * 8];
            bf[i] = *(const f16x8*)&sB[(wn + i * 16 + lr) * 32 + lq * 8];
        }
        #pragma unroll
        for (int mi = 0; mi < 4; ++mi)
            #pragma unroll
            for (int ni = 0; ni < 4; ++ni)
                acc[mi][ni] = __builtin_amdgcn_mfma_f32_16x16x32_f16(
                    af[mi], bf[ni], acc[mi][ni], 0, 0, 0);
        __syncthreads();  // reads done before next DMA overwrites
    }

    #pragma unroll
    for (int mi = 0; mi < 4; ++mi) {
        #pragma unroll
        for (int ni = 0; ni < 4; ++ni) {
            const int n = n0 + wn + ni * 16 + lr;
            const float bv = Bias[n];
            const int h = (n >> 6) & 15, d = n & 63;
            const int mbase = m0 + wm + mi * 16 + lq * 4;
            const int b = mbase >> 11, t0 = mbase & 2047;
            const int bh = b * 16 + h;
            if (s == 0) {        // q, pre-scaled by hd^-0.5 * log2(e)
                #pragma unroll
                for (int r = 0; r < 4; ++r)
                    qws[((size_t)bh * 2048 + t0 + r) * 64 + d] =
                        (_Float16)((acc[mi][ni][r] + bv) * 0.18033688f);
            } else if (s == 1) { // k
                #pragma unroll
                for (int r = 0; r < 4; ++r)
                    kws[((size_t)bh * 2048 + t0 + r) * 64 + d] =
                        (_Float16)(acc[mi][ni][r] + bv);
            } else {             // v transposed: [bh][d][t]
                f16x4 pk;
                #pragma unroll
                for (int r = 0; r < 4; ++r) pk[r] = (_Float16)(acc[mi][ni][r] + bv);
                *(f16x4*)&vtws[((size_t)bh * 64 + d) * 2048 + t0] = pk;
            }
        }
    }
}

// ---------------- K2: flash attention (PV-direct + T14, VGPR headroom) ----------------
__global__ __launch_bounds__(256, 3) void attn_kernel(
    const _Float16* __restrict__ qws,   // [64][2048][64], pre-scaled
    const _Float16* __restrict__ kws,   // [64][2048][64]
    const _Float16* __restrict__ vtws,  // [64][64][2048]
    _Float16* __restrict__ ows)         // [8192][1024]
{
    __shared__ _Float16 sK[64][72];     // 9 KB; stride 72: frag reads ~2-way = free
    __shared__ _Float16 sV[64][72];     // 9 KB
    const int bid = blockIdx.x;
    const int bh = (bid & 7) * 8 + ((bid >> 3) & 7);  // XCD-swizzle: bh's 16 qb share an XCD
    const int qb = bid >> 6;
    const int tid = threadIdx.x, wave = tid >> 6, lane = tid & 63;
    const int lr = lane & 15, lq = lane >> 4;

    // ---- Q frags direct from global (rows wave-exclusive, no reuse) ----
    const _Float16* gq = qws + ((size_t)bh * 2048 + qb * 128) * 64;
    f16x8 aQ[2][2];
    #pragma unroll
    for (int mb = 0; mb < 2; ++mb)
        #pragma unroll
        for (int ks = 0; ks < 2; ++ks)
            aQ[mb][ks] = *(const f16x8*)&gq[(wave * 32 + mb * 16 + lr) * 64 + ks * 32 + lq * 8];

    // ---- T14 staging: per-thread source pointers (rows srow, srow+32) ----
    const int srow = tid >> 3, scol = (tid & 7) * 8;
    const _Float16* gk = kws + ((size_t)bh * 2048 + srow) * 64 + scol;          // +4096/tile
    const _Float16* gv = vtws + (size_t)bh * 64 * 2048 + (size_t)srow * 2048 + scol;  // +64/tile

    uint4 rK0 = *(const uint4*)gk;
    uint4 rK1 = *(const uint4*)(gk + 32 * 64);
    uint4 rV0 = *(const uint4*)gv;
    uint4 rV1 = *(const uint4*)(gv + (size_t)32 * 2048);

    f32x4 o[2][4] = {};        // O^T: row=d=lq*4+reg, col=q=lr
    float l_loc[2] = {};       // per-lane partial l for q=lr

    for (int kt = 0; kt < 32; ++kt) {
        __syncthreads();  // prev-tile LDS reads done (kt=0: no-op); drains rK/rV loads
        *(uint4*)&sK[srow][scol]      = rK0;
        *(uint4*)&sK[srow + 32][scol] = rK1;
        *(uint4*)&sV[srow][scol]      = rV0;
        *(uint4*)&sV[srow + 32][scol] = rV1;
        __syncthreads();

        // ---- issue loads for kt+1 AFTER the barrier (its vmcnt(0) drain
        //      would otherwise expose the latency); consumed next iter ----
        if (kt < 31) {
            gk += 4096; gv += 64;
            rK0 = *(const uint4*)gk;
            rK1 = *(const uint4*)(gk + 32 * 64);
            rV0 = *(const uint4*)gv;
            rV1 = *(const uint4*)(gv + (size_t)32 * 2048);
        }

        // ---- S^T = K Q^T (swapped operands). C: row=key=lq*4+reg, col=q=lr ----
        f16x8 bK[2][4];
        #pragma unroll
        for (int ks = 0; ks < 2; ++ks)
            #pragma unroll
            for (int nb = 0; nb < 4; ++nb)
                bK[ks][nb] = *(const f16x8*)&sK[nb * 16 + lr][ks * 32 + lq * 8];
        f32x4 st[4][2] = {};   // [key-block][q-block]
        __builtin_amdgcn_s_setprio(1);
        #pragma unroll
        for (int nb = 0; nb < 4; ++nb)
            #pragma unroll
            for (int mb = 0; mb < 2; ++mb) {
                st[nb][mb] = __builtin_amdgcn_mfma_f32_16x16x32_f16(
                    bK[0][nb], aQ[mb][0], st[nb][mb], 0, 0, 0);
                st[nb][mb] = __builtin_amdgcn_mfma_f32_16x16x32_f16(
                    bK[1][nb], aQ[mb][1], st[nb][mb], 0, 0, 0);
            }
        __builtin_amdgcn_s_setprio(0);

        // ---- p = exp2(s'); pack in-register: st layout (key=lq*4+reg, q=lr)
        //      IS the 16x16x16 B-frag layout (k=lq*4+j, col=lr). No LDS. ----
        f16x4 pB16[4][2];
        #pragma unroll
        for (int nb = 0; nb < 4; ++nb)
            #pragma unroll
            for (int mb = 0; mb < 2; ++mb) {
                float e0 = exp2f(st[nb][mb][0]);
                float e1 = exp2f(st[nb][mb][1]);
                float e2 = exp2f(st[nb][mb][2]);
                float e3 = exp2f(st[nb][mb][3]);
                l_loc[mb] += (e0 + e1) + (e2 + e3);
                union { h16x2 v2[2]; f16x4 v4; } u;
                u.v2[0] = __builtin_amdgcn_cvt_pkrtz(e0, e1);
                u.v2[1] = __builtin_amdgcn_cvt_pkrtz(e2, e3);
                pB16[nb][mb] = u.v4;
            }

        // ---- O^T += V^T P^T via 16x16x16 MFMA (K=16 per key-block nb) ----
        __builtin_amdgcn_s_setprio(1);
        #pragma unroll
        for (int nb = 0; nb < 4; ++nb) {
            f16x4 vA16[4];
            #pragma unroll
            for (int db = 0; db < 4; ++db)  // A[row=d=db*16+lr][k=nb*16+lq*4+j]
                vA16[db] = *(const f16x4*)&sV[db * 16 + lr][nb * 16 + lq * 4];
            #pragma unroll
            for (int mb = 0; mb < 2; ++mb)
                #pragma unroll
                for (int db = 0; db < 4; ++db)
                    o[mb][db] = __builtin_amdgcn_mfma_f32_16x16x16f16(
                        vA16[db], pB16[nb][mb], o[mb][db], 0, 0, 0);
        }
        __builtin_amdgcn_s_setprio(0);
    }

    // ---- epilogue: l spans lanes {lr, lr+16, lr+32, lr+48} -> xor-reduce ----
    const int b = bh >> 4, h = bh & 15;
    #pragma unroll
    for (int mb = 0; mb < 2; ++mb) {
        float l = l_loc[mb];
        l += __shfl_xor(l, 16, 64);
        l += __shfl_xor(l, 32, 64);
        const float linv = 1.0f / l;    // every lane now holds full l[q=lr]
        const int t = qb * 128 + wave * 32 + mb * 16 + lr;
        #pragma unroll
        for (int db = 0; db < 4; ++db) {
            f16x4 pk;
            #pragma unroll
            for (int reg = 0; reg < 4; ++reg)
                pk[reg] = (_Float16)(o[mb][db][reg] * linv);
            *(f16x4*)&ows[((size_t)(b * 2048 + t)) * 1024 + h * 64 + db * 16 + lq * 4] = pk;
        }
    }
}

// ---------------- K3: proj GEMM (m97 structure) ----------------
// M=8192 N=1024 K=1024, fp32 out.
__global__ __launch_bounds__(256) void proj_gemm(
    const _Float16* __restrict__ A, const _Float16* __restrict__ W,
    const float* __restrict__ Bias, float* __restrict__ out)
{
    __shared__ _Float16 sA[128 * 32];
    __shared__ _Float16 sB[128 * 32];
    const int tid = threadIdx.x;
    const int wave = tid >> 6, lane = tid & 63;
    const int wm = (wave >> 1) * 64, wn = (wave & 1) * 64;
    const int lr = lane & 15, lq = lane >> 4;
    const int m0 = blockIdx.y * 128, n0 = blockIdx.x * 128;

    const int drow = wave * 16 + (lane >> 2);
    const int dcol = (lane & 3) * 8;
    _Float16* ldsA = sA + wave * 512;
    _Float16* ldsB = sB + wave * 512;
    const _Float16* gA = A + (size_t)(m0 + drow) * 1024 + dcol;
    const _Float16* gB = W + (size_t)(n0 + drow) * 1024 + dcol;

    f32x4 acc[4][4] = {};

    for (int k0 = 0; k0 < 1024; k0 += 32) {
        dma16(gA + k0, ldsA);
        dma16(gA + (size_t)64 * 1024 + k0, ldsA + 2048);
        dma16(gB + k0, ldsB);
        dma16(gB + (size_t)64 * 1024 + k0, ldsB + 2048);
        __syncthreads();
        f16x8 af[4], bf[4];
        #pragma unroll
        for (int i = 0; i < 4; ++i) {
            af[i] = *(const f16x8*)&sA[(wm + i * 16 + lr) * 32 + lq * 8];
            bf[i] = *(const f16x8*)&sB[(wn + i * 16 + lr) * 32 + lq * 8];
        }
        #pragma unroll
        for (int mi = 0; mi < 4; ++mi)
            #pragma unroll
            for (int ni = 0; ni < 4; ++ni)
                acc[mi][ni] = __builtin_amdgcn_mfma_f32_16x16x32_f16(
                    af[mi], bf[ni], acc[mi][ni], 0, 0, 0);
        __syncthreads();
    }

    #pragma unroll
    for (int mi = 0; mi < 4; ++mi) {
        #pragma unroll
        for (int ni = 0; ni < 4; ++ni) {
            const int n = n0 + wn + ni * 16 + lr;
            const float bv = Bias[n];
            #pragma unroll
            for (int r = 0; r < 4; ++r) {
                const int m = m0 + wm + mi * 16 + lq * 4 + r;
                out[(size_t)m * 1024 + n] = acc[mi][ni][r] + bv;
            }
        }
    }
}

// ---------------- launch ----------------
extern "C" void kernel_launch(void* const* d_in, const int* in_sizes, int n_in,
                              void* d_out, int out_size, void* d_ws, size_t ws_size,
                              hipStream_t stream) {
    const float* x      = (const float*)d_in[0];
    const float* qkv_w  = (const float*)d_in[1];
    const float* qkv_b  = (const float*)d_in[2];
    const float* proj_w = (const float*)d_in[3];
    const float* proj_b = (const float*)d_in[4];
    float* out = (float*)d_out;

    char* ws = (char*)d_ws;
    _Float16* qws  = (_Float16*)(ws);
    _Float16* kws  = (_Float16*)(ws + 16777216u);
    _Float16* vtws = (_Float16*)(ws + 33554432u);
    _Float16* ows  = (_Float16*)(ws + 50331648u);
    _Float16* Xh   = (_Float16*)(ws + 67108864u);
    _Float16* Wqh  = (_Float16*)(ws + 83886080u);
    _Float16* Wph  = (_Float16*)(ws + 90177536u);

    cvt_fp16<<<dim3(6144), 256, 0, stream>>>(x, qkv_w, proj_w, Xh, Wqh, Wph);
    qkv_gemm<<<dim3(24, 64), 256, 0, stream>>>(Xh, Wqh, qkv_b, qws, kws, vtws);
    attn_kernel<<<dim3(1024), 256, 0, stream>>>(qws, kws, vtws, ows);
    proj_gemm<<<dim3(8, 64), 256, 0, stream>>>(ows, Wph, proj_b, out);
}

// Round 7
// 314.585 us; speedup vs baseline: 1.0258x; 1.0258x over previous
//
#include <hip/hip_runtime.h>

// TinyAttention on MI355X, round 14.
//   K0: cvt x/qkv_w/proj_w fp32->fp16
//   K1: QKV GEMM, m97-style global_load_lds(16B) DMA
//   K2: flash attn = r11 (PV-direct 16x16x16, no sP, reg-staged two-barrier)
//       with QBLK=64: 2-wave/128-thread blocks, grid 2048 -> 8 blocks/CU
//       (was 4). Same waves/CU but 8 independent barrier domains: blocks
//       interleave staging-stall with compute. T14 prefetch REVERTED (refuted
//       r12/r13: spill, then FETCH +15MB L2-convoy desync, both slower).
//   K3: proj GEMM, m97-style, fp32 out
// B=4 T=2048 C=1024 H=16 hd=64. Inputs fp32, output fp32 (established r1-r3).

typedef _Float16 f16x8 __attribute__((ext_vector_type(8)));
typedef _Float16 f16x4 __attribute__((ext_vector_type(4)));
typedef __fp16 h16x2 __attribute__((ext_vector_type(2)));  // cvt_pkrtz native type
typedef float f32x4 __attribute__((ext_vector_type(4)));

__device__ __forceinline__ uint4 cvt8h(const float* p) {
    float4 a = *(const float4*)p, b = *(const float4*)(p + 4);
    union { _Float16 h[8]; uint4 u; } t;
    t.h[0] = (_Float16)a.x; t.h[1] = (_Float16)a.y;
    t.h[2] = (_Float16)a.z; t.h[3] = (_Float16)a.w;
    t.h[4] = (_Float16)b.x; t.h[5] = (_Float16)b.y;
    t.h[6] = (_Float16)b.z; t.h[7] = (_Float16)b.w;
    return t.u;
}

// async global->LDS DMA, 16 B/lane; LDS dest = wave-uniform base + lane*16
__device__ __forceinline__ void dma16(const _Float16* g, _Float16* l) {
    __builtin_amdgcn_global_load_lds(
        (const __attribute__((address_space(1))) unsigned int*)g,
        (__attribute__((address_space(3))) unsigned int*)l, 16, 0, 0);
}

// ---------------- K0: fp32 -> fp16 convert ----------------
__global__ __launch_bounds__(256) void cvt_fp16(
    const float* __restrict__ x, const float* __restrict__ w1,
    const float* __restrict__ w2,
    _Float16* __restrict__ xh, _Float16* __restrict__ w1h,
    _Float16* __restrict__ w2h)
{
    const int g = blockIdx.x * 256 + threadIdx.x;
    const float* src; _Float16* dst; int off;
    if (g < 1048576)      { src = x;  dst = xh;  off = g; }
    else if (g < 1441792) { src = w1; dst = w1h; off = g - 1048576; }
    else                  { src = w2; dst = w2h; off = g - 1441792; }
    const size_t e = (size_t)off * 8;
    *(uint4*)(dst + e) = cvt8h(src + e);
}

// ---------------- K1: QKV GEMM (m97 structure) ----------------
// M=8192 N=3072 K=1024. q pre-scaled by 0.125*log2e; v transposed [bh][d][t].
__global__ __launch_bounds__(256) void qkv_gemm(
    const _Float16* __restrict__ X, const _Float16* __restrict__ W,
    const float* __restrict__ Bias,
    _Float16* __restrict__ qws, _Float16* __restrict__ kws,
    _Float16* __restrict__ vtws)
{
    __shared__ _Float16 sA[128 * 32];   // 8 KB, unpadded (DMA layout)
    __shared__ _Float16 sB[128 * 32];
    const int tid = threadIdx.x;
    const int wave = tid >> 6, lane = tid & 63;
    const int wm = (wave >> 1) * 64, wn = (wave & 1) * 64;
    const int lr = lane & 15, lq = lane >> 4;
    const int m0 = blockIdx.y * 128, n0 = blockIdx.x * 128;
    const int s = n0 >> 10;

    const int drow = wave * 16 + (lane >> 2);
    const int dcol = (lane & 3) * 8;
    _Float16* ldsA = sA + wave * 512;
    _Float16* ldsB = sB + wave * 512;
    const _Float16* gA = X + (size_t)(m0 + drow) * 1024 + dcol;
    const _Float16* gB = W + (size_t)(n0 + drow) * 1024 + dcol;

    f32x4 acc[4][4] = {};

    for (int k0 = 0; k0 < 1024; k0 += 32) {
        dma16(gA + k0, ldsA);
        dma16(gA + (size_t)64 * 1024 + k0, ldsA + 2048);
        dma16(gB + k0, ldsB);
        dma16(gB + (size_t)64 * 1024 + k0, ldsB + 2048);
        __syncthreads();  // drains DMA for all waves
        f16x8 af[4], bf[4];
        #pragma unroll
        for (int i = 0; i < 4; ++i) {
            af[i] = *(const f16x8*)&sA[(wm + i * 16 + lr) * 32 + lq * 8];
            bf[i] = *(const f16x8*)&sB[(wn + i * 16 + lr) * 32 + lq * 8];
        }
        #pragma unroll
        for (int mi = 0; mi < 4; ++mi)
            #pragma unroll
            for (int ni = 0; ni < 4; ++ni)
                acc[mi][ni] = __builtin_amdgcn_mfma_f32_16x16x32_f16(
                    af[mi], bf[ni], acc[mi][ni], 0, 0, 0);
        __syncthreads();  // reads done before next DMA overwrites
    }

    #pragma unroll
    for (int mi = 0; mi < 4; ++mi) {
        #pragma unroll
        for (int ni = 0; ni < 4; ++ni) {
            const int n = n0 + wn + ni * 16 + lr;
            const float bv = Bias[n];
            const int h = (n >> 6) & 15, d = n & 63;
            const int mbase = m0 + wm + mi * 16 + lq * 4;
            const int b = mbase >> 11, t0 = mbase & 2047;
            const int bh = b * 16 + h;
            if (s == 0) {        // q, pre-scaled by hd^-0.5 * log2(e)
                #pragma unroll
                for (int r = 0; r < 4; ++r)
                    qws[((size_t)bh * 2048 + t0 + r) * 64 + d] =
                        (_Float16)((acc[mi][ni][r] + bv) * 0.18033688f);
            } else if (s == 1) { // k
                #pragma unroll
                for (int r = 0; r < 4; ++r)
                    kws[((size_t)bh * 2048 + t0 + r) * 64 + d] =
                        (_Float16)(acc[mi][ni][r] + bv);
            } else {             // v transposed: [bh][d][t]
                f16x4 pk;
                #pragma unroll
                for (int r = 0; r < 4; ++r) pk[r] = (_Float16)(acc[mi][ni][r] + bv);
                *(f16x4*)&vtws[((size_t)bh * 64 + d) * 2048 + t0] = pk;
            }
        }
    }
}

// ---------------- K2: flash attention (QBLK=64, 2 waves, 8 blocks/CU) ----------------
__global__ __launch_bounds__(128, 4) void attn_kernel(
    const _Float16* __restrict__ qws,   // [64][2048][64], pre-scaled
    const _Float16* __restrict__ kws,   // [64][2048][64]
    const _Float16* __restrict__ vtws,  // [64][64][2048]
    _Float16* __restrict__ ows)         // [8192][1024]
{
    __shared__ _Float16 sK[64][72];     // 9 KB; stride 72: frag reads ~2-way = free
    __shared__ _Float16 sV[64][72];     // 9 KB
    const int bid = blockIdx.x;
    const int bh = (bid & 7) * 8 + ((bid >> 3) & 7);  // XCD-swizzle: bh's 32 qb share an XCD
    const int qb = bid >> 6;                          // 0..31 (64 q-rows each)
    const int tid = threadIdx.x, wave = tid >> 6, lane = tid & 63;
    const int lr = lane & 15, lq = lane >> 4;

    // ---- Q frags direct from global (rows wave-exclusive, no reuse) ----
    const _Float16* gq = qws + ((size_t)bh * 2048 + qb * 64) * 64;
    f16x8 aQ[2][2];
    #pragma unroll
    for (int mb = 0; mb < 2; ++mb)
        #pragma unroll
        for (int ks = 0; ks < 2; ++ks)
            aQ[mb][ks] = *(const f16x8*)&gq[(wave * 32 + mb * 16 + lr) * 64 + ks * 32 + lq * 8];

    f32x4 o[2][4] = {};        // O^T: row=d=lq*4+reg, col=q=lr
    float l_loc[2] = {};       // per-lane partial l for q=lr

    for (int kt = 0; kt < 32; ++kt) {
        const _Float16* gk = kws + ((size_t)bh * 2048 + kt * 64) * 64;
        const _Float16* gv = vtws + (size_t)bh * 64 * 2048 + kt * 64;
        __syncthreads();  // prev-tile LDS reads done (kt=0: no-op)
        for (int i = tid; i < 512; i += 128) {
            const int row = i >> 3, c = (i & 7) * 8;
            *(uint4*)&sK[row][c] = *(const uint4*)&gk[row * 64 + c];
            *(uint4*)&sV[row][c] = *(const uint4*)&gv[(size_t)row * 2048 + c];
        }
        __syncthreads();

        // ---- S^T = K Q^T (swapped operands). C: row=key=lq*4+reg, col=q=lr ----
        f16x8 bK[2][4];
        #pragma unroll
        for (int ks = 0; ks < 2; ++ks)
            #pragma unroll
            for (int nb = 0; nb < 4; ++nb)
                bK[ks][nb] = *(const f16x8*)&sK[nb * 16 + lr][ks * 32 + lq * 8];
        f32x4 st[4][2] = {};   // [key-block][q-block]
        __builtin_amdgcn_s_setprio(1);
        #pragma unroll
        for (int nb = 0; nb < 4; ++nb)
            #pragma unroll
            for (int mb = 0; mb < 2; ++mb) {
                st[nb][mb] = __builtin_amdgcn_mfma_f32_16x16x32_f16(
                    bK[0][nb], aQ[mb][0], st[nb][mb], 0, 0, 0);
                st[nb][mb] = __builtin_amdgcn_mfma_f32_16x16x32_f16(
                    bK[1][nb], aQ[mb][1], st[nb][mb], 0, 0, 0);
            }
        __builtin_amdgcn_s_setprio(0);

        // ---- p = exp2(s'); pack in-register: st layout (key=lq*4+reg, q=lr)
        //      IS the 16x16x16 B-frag layout (k=lq*4+j, col=lr). No LDS. ----
        f16x4 pB16[4][2];
        #pragma unroll
        for (int nb = 0; nb < 4; ++nb)
            #pragma unroll
            for (int mb = 0; mb < 2; ++mb) {
                float e0 = exp2f(st[nb][mb][0]);
                float e1 = exp2f(st[nb][mb][1]);
                float e2 = exp2f(st[nb][mb][2]);
                float e3 = exp2f(st[nb][mb][3]);
                l_loc[mb] += (e0 + e1) + (e2 + e3);
                union { h16x2 v2[2]; f16x4 v4; } u;
                u.v2[0] = __builtin_amdgcn_cvt_pkrtz(e0, e1);
                u.v2[1] = __builtin_amdgcn_cvt_pkrtz(e2, e3);
                pB16[nb][mb] = u.v4;
            }

        // ---- O^T += V^T P^T via 16x16x16 MFMA (K=16 per key-block nb) ----
        __builtin_amdgcn_s_setprio(1);
        #pragma unroll
        for (int nb = 0; nb < 4; ++nb) {
            f16x4 vA16[4];
            #pragma unroll
            for (int db = 0; db < 4; ++db)  // A[row=d=db*16+lr][k=nb*16+lq*4+j]
                vA16[db] = *(const f16x4*)&sV[db * 16 + lr][nb * 16 + lq * 4];
            #pragma unroll
            for (int mb = 0; mb < 2; ++mb)
                #pragma unroll
                for (int db = 0; db < 4; ++db)
                    o[mb][db] = __builtin_amdgcn_mfma_f32_16x16x16f16(
                        vA16[db], pB16[nb][mb], o[mb][db], 0, 0, 0);
        }
        __builtin_amdgcn_s_setprio(0);
    }

    // ---- epilogue: l spans lanes {lr, lr+16, lr+32, lr+48} -> xor-reduce ----
    const int b = bh >> 4, h = bh & 15;
    #pragma unroll
    for (int mb = 0; mb < 2; ++mb) {
        float l = l_loc[mb];
        l += __shfl_xor(l, 16, 64);
        l += __shfl_xor(l, 32, 64);
        const float linv = 1.0f / l;    // every lane now holds full l[q=lr]
        const int t = qb * 64 + wave * 32 + mb * 16 + lr;
        #pragma unroll
        for (int db = 0; db < 4; ++db) {
            f16x4 pk;
            #pragma unroll
            for (int reg = 0; reg < 4; ++reg)
                pk[reg] = (_Float16)(o[mb][db][reg] * linv);
            *(f16x4*)&ows[((size_t)(b * 2048 + t)) * 1024 + h * 64 + db * 16 + lq * 4] = pk;
        }
    }
}

// ---------------- K3: proj GEMM (m97 structure) ----------------
// M=8192 N=1024 K=1024, fp32 out.
__global__ __launch_bounds__(256) void proj_gemm(
    const _Float16* __restrict__ A, const _Float16* __restrict__ W,
    const float* __restrict__ Bias, float* __restrict__ out)
{
    __shared__ _Float16 sA[128 * 32];
    __shared__ _Float16 sB[128 * 32];
    const int tid = threadIdx.x;
    const int wave = tid >> 6, lane = tid & 63;
    const int wm = (wave >> 1) * 64, wn = (wave & 1) * 64;
    const int lr = lane & 15, lq = lane >> 4;
    const int m0 = blockIdx.y * 128, n0 = blockIdx.x * 128;

    const int drow = wave * 16 + (lane >> 2);
    const int dcol = (lane & 3) * 8;
    _Float16* ldsA = sA + wave * 512;
    _Float16* ldsB = sB + wave * 512;
    const _Float16* gA = A + (size_t)(m0 + drow) * 1024 + dcol;
    const _Float16* gB = W + (size_t)(n0 + drow) * 1024 + dcol;

    f32x4 acc[4][4] = {};

    for (int k0 = 0; k0 < 1024; k0 += 32) {
        dma16(gA + k0, ldsA);
        dma16(gA + (size_t)64 * 1024 + k0, ldsA + 2048);
        dma16(gB + k0, ldsB);
        dma16(gB + (size_t)64 * 1024 + k0, ldsB + 2048);
        __syncthreads();
        f16x8 af[4], bf[4];
        #pragma unroll
        for (int i = 0; i < 4; ++i) {
            af[i] = *(const f16x8*)&sA[(wm + i * 16 + lr) * 32 + lq * 8];
            bf[i] = *(const f16x8*)&sB[(wn + i * 16 + lr) * 32 + lq * 8];
        }
        #pragma unroll
        for (int mi = 0; mi < 4; ++mi)
            #pragma unroll
            for (int ni = 0; ni < 4; ++ni)
                acc[mi][ni] = __builtin_amdgcn_mfma_f32_16x16x32_f16(
                    af[mi], bf[ni], acc[mi][ni], 0, 0, 0);
        __syncthreads();
    }

    #pragma unroll
    for (int mi = 0; mi < 4; ++mi) {
        #pragma unroll
        for (int ni = 0; ni < 4; ++ni) {
            const int n = n0 + wn + ni * 16 + lr;
            const float bv = Bias[n];
            #pragma unroll
            for (int r = 0; r < 4; ++r) {
                const int m = m0 + wm + mi * 16 + lq * 4 + r;
                out[(size_t)m * 1024 + n] = acc[mi][ni][r] + bv;
            }
        }
    }
}

// ---------------- launch ----------------
extern "C" void kernel_launch(void* const* d_in, const int* in_sizes, int n_in,
                              void* d_out, int out_size, void* d_ws, size_t ws_size,
                              hipStream_t stream) {
    const float* x      = (const float*)d_in[0];
    const float* qkv_w  = (const float*)d_in[1];
    const float* qkv_b  = (const float*)d_in[2];
    const float* proj_w = (const float*)d_in[3];
    const float* proj_b = (const float*)d_in[4];
    float* out = (float*)d_out;

    char* ws = (char*)d_ws;
    _Float16* qws  = (_Float16*)(ws);
    _Float16* kws  = (_Float16*)(ws + 16777216u);
    _Float16* vtws = (_Float16*)(ws + 33554432u);
    _Float16* ows  = (_Float16*)(ws + 50331648u);
    _Float16* Xh   = (_Float16*)(ws + 67108864u);
    _Float16* Wqh  = (_Float16*)(ws + 83886080u);
    _Float16* Wph  = (_Float16*)(ws + 90177536u);

    cvt_fp16<<<dim3(6144), 256, 0, stream>>>(x, qkv_w, proj_w, Xh, Wqh, Wph);
    qkv_gemm<<<dim3(24, 64), 256, 0, stream>>>(Xh, Wqh, qkv_b, qws, kws, vtws);
    attn_kernel<<<dim3(2048), 128, 0, stream>>>(qws, kws, vtws, ows);
    proj_gemm<<<dim3(8, 64), 256, 0, stream>>>(ows, Wph, proj_b, out);
}

// Round 8
// 302.040 us; speedup vs baseline: 1.0684x; 1.0415x over previous
//
#include <hip/hip_runtime.h>

// TinyAttention on MI355X, round 15.
//   K0: cvt x/qkv_w/proj_w fp32->fp16
//   K1: QKV GEMM, m97-style global_load_lds(16B) DMA
//   K2: flash attn = r11 structure (QBLK=128, 4 waves, two-barrier, PV-direct
//       16x16x16, no sP) + K/V staging via global_load_lds DMA into LINEAR
//       [64][64] LDS with pre-swizzled source (byte ^= (row&7)<<4, r9-proven
//       bijective pairing) and the same XOR on frag reads. Kills both the
//       staging-write bank conflicts (DMA dest is linear = conflict-free) and
//       the VGPR round-trip VALU work; read conflicts drop per r9 (6.3M incl
//       sP -> ~4M without). r14's QBLK=64 split REVERTED (refuted: +7us).
//   K3: proj GEMM, m97-style, fp32 out
// B=4 T=2048 C=1024 H=16 hd=64. Inputs fp32, output fp32 (established r1-r3).

typedef _Float16 f16x8 __attribute__((ext_vector_type(8)));
typedef _Float16 f16x4 __attribute__((ext_vector_type(4)));
typedef __fp16 h16x2 __attribute__((ext_vector_type(2)));  // cvt_pkrtz native type
typedef float f32x4 __attribute__((ext_vector_type(4)));

__device__ __forceinline__ uint4 cvt8h(const float* p) {
    float4 a = *(const float4*)p, b = *(const float4*)(p + 4);
    union { _Float16 h[8]; uint4 u; } t;
    t.h[0] = (_Float16)a.x; t.h[1] = (_Float16)a.y;
    t.h[2] = (_Float16)a.z; t.h[3] = (_Float16)a.w;
    t.h[4] = (_Float16)b.x; t.h[5] = (_Float16)b.y;
    t.h[6] = (_Float16)b.z; t.h[7] = (_Float16)b.w;
    return t.u;
}

// async global->LDS DMA, 16 B/lane; LDS dest = wave-uniform base + lane*16
__device__ __forceinline__ void dma16(const _Float16* g, _Float16* l) {
    __builtin_amdgcn_global_load_lds(
        (const __attribute__((address_space(1))) unsigned int*)g,
        (__attribute__((address_space(3))) unsigned int*)l, 16, 0, 0);
}

// ---------------- K0: fp32 -> fp16 convert ----------------
__global__ __launch_bounds__(256) void cvt_fp16(
    const float* __restrict__ x, const float* __restrict__ w1,
    const float* __restrict__ w2,
    _Float16* __restrict__ xh, _Float16* __restrict__ w1h,
    _Float16* __restrict__ w2h)
{
    const int g = blockIdx.x * 256 + threadIdx.x;
    const float* src; _Float16* dst; int off;
    if (g < 1048576)      { src = x;  dst = xh;  off = g; }
    else if (g < 1441792) { src = w1; dst = w1h; off = g - 1048576; }
    else                  { src = w2; dst = w2h; off = g - 1441792; }
    const size_t e = (size_t)off * 8;
    *(uint4*)(dst + e) = cvt8h(src + e);
}

// ---------------- K1: QKV GEMM (m97 structure) ----------------
// M=8192 N=3072 K=1024. q pre-scaled by 0.125*log2e; v transposed [bh][d][t].
__global__ __launch_bounds__(256) void qkv_gemm(
    const _Float16* __restrict__ X, const _Float16* __restrict__ W,
    const float* __restrict__ Bias,
    _Float16* __restrict__ qws, _Float16* __restrict__ kws,
    _Float16* __restrict__ vtws)
{
    __shared__ _Float16 sA[128 * 32];   // 8 KB, unpadded (DMA layout)
    __shared__ _Float16 sB[128 * 32];
    const int tid = threadIdx.x;
    const int wave = tid >> 6, lane = tid & 63;
    const int wm = (wave >> 1) * 64, wn = (wave & 1) * 64;
    const int lr = lane & 15, lq = lane >> 4;
    const int m0 = blockIdx.y * 128, n0 = blockIdx.x * 128;
    const int s = n0 >> 10;

    const int drow = wave * 16 + (lane >> 2);
    const int dcol = (lane & 3) * 8;
    _Float16* ldsA = sA + wave * 512;
    _Float16* ldsB = sB + wave * 512;
    const _Float16* gA = X + (size_t)(m0 + drow) * 1024 + dcol;
    const _Float16* gB = W + (size_t)(n0 + drow) * 1024 + dcol;

    f32x4 acc[4][4] = {};

    for (int k0 = 0; k0 < 1024; k0 += 32) {
        dma16(gA + k0, ldsA);
        dma16(gA + (size_t)64 * 1024 + k0, ldsA + 2048);
        dma16(gB + k0, ldsB);
        dma16(gB + (size_t)64 * 1024 + k0, ldsB + 2048);
        __syncthreads();  // drains DMA for all waves
        f16x8 af[4], bf[4];
        #pragma unroll
        for (int i = 0; i < 4; ++i) {
            af[i] = *(const f16x8*)&sA[(wm + i * 16 + lr) * 32 + lq * 8];
            bf[i] = *(const f16x8*)&sB[(wn + i * 16 + lr) * 32 + lq * 8];
        }
        #pragma unroll
        for (int mi = 0; mi < 4; ++mi)
            #pragma unroll
            for (int ni = 0; ni < 4; ++ni)
                acc[mi][ni] = __builtin_amdgcn_mfma_f32_16x16x32_f16(
                    af[mi], bf[ni], acc[mi][ni], 0, 0, 0);
        __syncthreads();  // reads done before next DMA overwrites
    }

    #pragma unroll
    for (int mi = 0; mi < 4; ++mi) {
        #pragma unroll
        for (int ni = 0; ni < 4; ++ni) {
            const int n = n0 + wn + ni * 16 + lr;
            const float bv = Bias[n];
            const int h = (n >> 6) & 15, d = n & 63;
            const int mbase = m0 + wm + mi * 16 + lq * 4;
            const int b = mbase >> 11, t0 = mbase & 2047;
            const int bh = b * 16 + h;
            if (s == 0) {        // q, pre-scaled by hd^-0.5 * log2(e)
                #pragma unroll
                for (int r = 0; r < 4; ++r)
                    qws[((size_t)bh * 2048 + t0 + r) * 64 + d] =
                        (_Float16)((acc[mi][ni][r] + bv) * 0.18033688f);
            } else if (s == 1) { // k
                #pragma unroll
                for (int r = 0; r < 4; ++r)
                    kws[((size_t)bh * 2048 + t0 + r) * 64 + d] =
                        (_Float16)(acc[mi][ni][r] + bv);
            } else {             // v transposed: [bh][d][t]
                f16x4 pk;
                #pragma unroll
                for (int r = 0; r < 4; ++r) pk[r] = (_Float16)(acc[mi][ni][r] + bv);
                *(f16x4*)&vtws[((size_t)bh * 64 + d) * 2048 + t0] = pk;
            }
        }
    }
}

// ---------------- K2: flash attention (DMA-staged swizzled K/V, PV-direct) ----------------
__global__ __launch_bounds__(256, 4) void attn_kernel(
    const _Float16* __restrict__ qws,   // [64][2048][64], pre-scaled
    const _Float16* __restrict__ kws,   // [64][2048][64]
    const _Float16* __restrict__ vtws,  // [64][64][2048]
    _Float16* __restrict__ ows)         // [8192][1024]
{
    __shared__ _Float16 sK[64][64];     // 8 KB, linear (DMA dest), source pre-swizzled
    __shared__ _Float16 sV[64][64];     // 8 KB
    const int bid = blockIdx.x;
    const int bh = (bid & 7) * 8 + ((bid >> 3) & 7);  // XCD-swizzle: bh's 16 qb share an XCD
    const int qb = bid >> 6;
    const int tid = threadIdx.x, wave = tid >> 6, lane = tid & 63;
    const int lr = lane & 15, lq = lane >> 4;

    // ---- Q frags direct from global (rows wave-exclusive, no reuse) ----
    const _Float16* gq = qws + ((size_t)bh * 2048 + qb * 128) * 64;
    f16x8 aQ[2][2];
    #pragma unroll
    for (int mb = 0; mb < 2; ++mb)
        #pragma unroll
        for (int ks = 0; ks < 2; ++ks)
            aQ[mb][ks] = *(const f16x8*)&gq[(wave * 32 + mb * 16 + lr) * 64 + ks * 32 + lq * 8];

    // ---- DMA staging: linear dest rows [wave*8+(lane>>3)] (+32 for 2nd call),
    //      source col pre-swizzled with the involution byte^=((row&7)<<4) ----
    const int l8 = lane >> 3;
    const int swzcol = (((lane & 7) * 16) ^ (l8 << 4)) >> 1;  // halves, 0..63
    const int krow = wave * 8 + l8;                           // row&7 == l8
    const _Float16* gk = kws + (size_t)bh * 2048 * 64 + (size_t)krow * 64 + swzcol;
    const _Float16* gv = vtws + (size_t)bh * 64 * 2048 + (size_t)krow * 2048 + swzcol;
    _Float16* dK = &sK[0][0] + wave * 512;
    _Float16* dV = &sV[0][0] + wave * 512;

    // swizzled frag column indices (halves); row parity r7 = lr&7
    const int r7 = lr & 7;
    const int cidx0 = ((lq * 16) ^ (r7 << 4)) >> 1;         // ks=0 (b128 K/V-8wide)
    const int cidx1 = ((64 + lq * 16) ^ (r7 << 4)) >> 1;    // ks=1

    f32x4 o[2][4] = {};        // O^T: row=d=lq*4+reg, col=q=lr
    float l_loc[2] = {};       // per-lane partial l for q=lr

    for (int kt = 0; kt < 32; ++kt) {
        __syncthreads();  // prev-tile LDS reads done (kt=0: no-op)
        dma16(gk,                     dK);
        dma16(gk + 32 * 64,           dK + 2048);
        dma16(gv,                     dV);
        dma16(gv + (size_t)32 * 2048, dV + 2048);
        gk += 4096; gv += 64;
        __syncthreads();  // drains DMA for all waves

        // ---- S^T = K Q^T (swapped operands). C: row=key=lq*4+reg, col=q=lr ----
        f16x8 bK[2][4];
        #pragma unroll
        for (int nb = 0; nb < 4; ++nb) {
            bK[0][nb] = *(const f16x8*)&sK[nb * 16 + lr][cidx0];
            bK[1][nb] = *(const f16x8*)&sK[nb * 16 + lr][cidx1];
        }
        f32x4 st[4][2] = {};   // [key-block][q-block]
        __builtin_amdgcn_s_setprio(1);
        #pragma unroll
        for (int nb = 0; nb < 4; ++nb)
            #pragma unroll
            for (int mb = 0; mb < 2; ++mb) {
                st[nb][mb] = __builtin_amdgcn_mfma_f32_16x16x32_f16(
                    bK[0][nb], aQ[mb][0], st[nb][mb], 0, 0, 0);
                st[nb][mb] = __builtin_amdgcn_mfma_f32_16x16x32_f16(
                    bK[1][nb], aQ[mb][1], st[nb][mb], 0, 0, 0);
            }
        __builtin_amdgcn_s_setprio(0);

        // ---- p = exp2(s'); pack in-register: st layout (key=lq*4+reg, q=lr)
        //      IS the 16x16x16 B-frag layout (k=lq*4+j, col=lr). No LDS. ----
        f16x4 pB16[4][2];
        #pragma unroll
        for (int nb = 0; nb < 4; ++nb)
            #pragma unroll
            for (int mb = 0; mb < 2; ++mb) {
                float e0 = exp2f(st[nb][mb][0]);
                float e1 = exp2f(st[nb][mb][1]);
                float e2 = exp2f(st[nb][mb][2]);
                float e3 = exp2f(st[nb][mb][3]);
                l_loc[mb] += (e0 + e1) + (e2 + e3);
                union { h16x2 v2[2]; f16x4 v4; } u;
                u.v2[0] = __builtin_amdgcn_cvt_pkrtz(e0, e1);
                u.v2[1] = __builtin_amdgcn_cvt_pkrtz(e2, e3);
                pB16[nb][mb] = u.v4;
            }

        // ---- O^T += V^T P^T via 16x16x16 MFMA (K=16 per key-block nb) ----
        __builtin_amdgcn_s_setprio(1);
        #pragma unroll
        for (int nb = 0; nb < 4; ++nb) {
            f16x4 vA16[4];
            #pragma unroll
            for (int db = 0; db < 4; ++db)  // A[row=d=db*16+lr][k=nb*16+lq*4+j], swizzled col
                vA16[db] = *(const f16x4*)&sV[db * 16 + lr]
                    [((nb * 32 + lq * 8) ^ (r7 << 4)) >> 1];
            #pragma unroll
            for (int mb = 0; mb < 2; ++mb)
                #pragma unroll
                for (int db = 0; db < 4; ++db)
                    o[mb][db] = __builtin_amdgcn_mfma_f32_16x16x16f16(
                        vA16[db], pB16[nb][mb], o[mb][db], 0, 0, 0);
        }
        __builtin_amdgcn_s_setprio(0);
    }

    // ---- epilogue: l spans lanes {lr, lr+16, lr+32, lr+48} -> xor-reduce ----
    const int b = bh >> 4, h = bh & 15;
    #pragma unroll
    for (int mb = 0; mb < 2; ++mb) {
        float l = l_loc[mb];
        l += __shfl_xor(l, 16, 64);
        l += __shfl_xor(l, 32, 64);
        const float linv = 1.0f / l;    // every lane now holds full l[q=lr]
        const int t = qb * 128 + wave * 32 + mb * 16 + lr;
        #pragma unroll
        for (int db = 0; db < 4; ++db) {
            f16x4 pk;
            #pragma unroll
            for (int reg = 0; reg < 4; ++reg)
                pk[reg] = (_Float16)(o[mb][db][reg] * linv);
            *(f16x4*)&ows[((size_t)(b * 2048 + t)) * 1024 + h * 64 + db * 16 + lq * 4] = pk;
        }
    }
}

// ---------------- K3: proj GEMM (m97 structure) ----------------
// M=8192 N=1024 K=1024, fp32 out.
__global__ __launch_bounds__(256) void proj_gemm(
    const _Float16* __restrict__ A, const _Float16* __restrict__ W,
    const float* __restrict__ Bias, float* __restrict__ out)
{
    __shared__ _Float16 sA[128 * 32];
    __shared__ _Float16 sB[128 * 32];
    const int tid = threadIdx.x;
    const int wave = tid >> 6, lane = tid & 63;
    const int wm = (wave >> 1) * 64, wn = (wave & 1) * 64;
    const int lr = lane & 15, lq = lane >> 4;
    const int m0 = blockIdx.y * 128, n0 = blockIdx.x * 128;

    const int drow = wave * 16 + (lane >> 2);
    const int dcol = (lane & 3) * 8;
    _Float16* ldsA = sA + wave * 512;
    _Float16* ldsB = sB + wave * 512;
    const _Float16* gA = A + (size_t)(m0 + drow) * 1024 + dcol;
    const _Float16* gB = W + (size_t)(n0 + drow) * 1024 + dcol;

    f32x4 acc[4][4] = {};

    for (int k0 = 0; k0 < 1024; k0 += 32) {
        dma16(gA + k0, ldsA);
        dma16(gA + (size_t)64 * 1024 + k0, ldsA + 2048);
        dma16(gB + k0, ldsB);
        dma16(gB + (size_t)64 * 1024 + k0, ldsB + 2048);
        __syncthreads();
        f16x8 af[4], bf[4];
        #pragma unroll
        for (int i = 0; i < 4; ++i) {
            af[i] = *(const f16x8*)&sA[(wm + i * 16 + lr) * 32 + lq * 8];
            bf[i] = *(const f16x8*)&sB[(wn + i * 16 + lr) * 32 + lq * 8];
        }
        #pragma unroll
        for (int mi = 0; mi < 4; ++mi)
            #pragma unroll
            for (int ni = 0; ni < 4; ++ni)
                acc[mi][ni] = __builtin_amdgcn_mfma_f32_16x16x32_f16(
                    af[mi], bf[ni], acc[mi][ni], 0, 0, 0);
        __syncthreads();
    }

    #pragma unroll
    for (int mi = 0; mi < 4; ++mi) {
        #pragma unroll
        for (int ni = 0; ni < 4; ++ni) {
            const int n = n0 + wn + ni * 16 + lr;
            const float bv = Bias[n];
            #pragma unroll
            for (int r = 0; r < 4; ++r) {
                const int m = m0 + wm + mi * 16 + lq * 4 + r;
                out[(size_t)m * 1024 + n] = acc[mi][ni][r] + bv;
            }
        }
    }
}

// ---------------- launch ----------------
extern "C" void kernel_launch(void* const* d_in, const int* in_sizes, int n_in,
                              void* d_out, int out_size, void* d_ws, size_t ws_size,
                              hipStream_t stream) {
    const float* x      = (const float*)d_in[0];
    const float* qkv_w  = (const float*)d_in[1];
    const float* qkv_b  = (const float*)d_in[2];
    const float* proj_w = (const float*)d_in[3];
    const float* proj_b = (const float*)d_in[4];
    float* out = (float*)d_out;

    char* ws = (char*)d_ws;
    _Float16* qws  = (_Float16*)(ws);
    _Float16* kws  = (_Float16*)(ws + 16777216u);
    _Float16* vtws = (_Float16*)(ws + 33554432u);
    _Float16* ows  = (_Float16*)(ws + 50331648u);
    _Float16* Xh   = (_Float16*)(ws + 67108864u);
    _Float16* Wqh  = (_Float16*)(ws + 83886080u);
    _Float16* Wph  = (_Float16*)(ws + 90177536u);

    cvt_fp16<<<dim3(6144), 256, 0, stream>>>(x, qkv_w, proj_w, Xh, Wqh, Wph);
    qkv_gemm<<<dim3(24, 64), 256, 0, stream>>>(Xh, Wqh, qkv_b, qws, kws, vtws);
    attn_kernel<<<dim3(1024), 256, 0, stream>>>(qws, kws, vtws, ows);
    proj_gemm<<<dim3(8, 64), 256, 0, stream>>>(ows, Wph, proj_b, out);
}